// Round 7
// baseline (141.051 us; speedup 1.0000x reference)
//
#include <hip/hip_runtime.h>
#include <hip/hip_bf16.h>

#define N_TOTAL 384
#define BS 128
#define PD 8
#define D_FEAT 131072
#define EPS 1e-6f

#define NSTRIP 256
#define COLS_PER (D_FEAT / NSTRIP)   // 512 cols per strip
#define CHUNK 32
#define NCH (COLS_PER / CHUNK)       // 16 chunks per strip
#define SROWS 256                    // rows staged per flavor
#define LROW 64                      // LDS row stride (bytes), XOR-swizzled, no pad

typedef __attribute__((ext_vector_type(4))) float f32x4;
typedef __attribute__((ext_vector_type(8))) __bf16 bf16x8;
typedef __attribute__((ext_vector_type(4))) __bf16 bf16x4;

// Flavors: F0 = tiles (0,0),(0,1); F1 = (1,1),(1,2); F2 = (2,2),(0,2).
// Each flavor stages 4 row-bands (64 rows each); SLOT maps global band -> LDS slot.
static __device__ const int BANDROW[3][4] = {{0,1,2,3},{2,3,4,5},{0,1,4,5}};
static __device__ const int SLOT[3][6]    = {{0,1,2,3,9,9},{9,9,0,1,2,3},{0,1,9,9,2,3}};
static __device__ const int TIt[3][2]     = {{0,0},{1,1},{2,0}};
static __device__ const int TJt[3][2]     = {{0,1},{1,2},{2,2}};

// Symmetric accessor: only upper-triangular 128-tiles of G are populated.
__device__ __forceinline__ float gsym(const float* __restrict__ G, int i, int j) {
    return ((i >> 7) <= (j >> 7)) ? G[(size_t)i * N_TOTAL + j]
                                  : G[(size_t)j * N_TOTAL + i];
}

// ---------------- fused: read X (fp32) once, cvt in-reg, Gram via MFMA ----------------
__global__ __launch_bounds__(512, 4) void gram_fused_kernel(const float* __restrict__ X,
                                                            float* __restrict__ G) {
    __shared__ char sm[2][SROWS * LROW];   // 2 x 16 KB, bf16 [256][32], XOR-swizzled

    // XCD swizzle: the 3 flavors of a strip land on the same XCD (L2 pair-reuse).
    const int B      = blockIdx.x;
    const int x      = B & 7;
    const int i      = B >> 3;
    const int flavor = i % 3;
    const int strip  = x + 8 * (i / 3);

    const int tid  = threadIdx.x;
    const int wave = tid >> 6;
    const int lane = tid & 63;
    const int r16  = lane & 15;
    const int kg   = lane >> 4;

    // ---- compute assignment: one 64x64 subtile per wave
    const int sub   = wave & 3;
    const int tI    = TIt[flavor][wave >> 2];
    const int tJ    = TJt[flavor][wave >> 2];
    const int lrowA = SLOT[flavor][2 * tI + (sub >> 1)] * 64;
    const int lrowB = SLOT[flavor][2 * tJ + (sub & 1)] * 64;
    const int xsw   = (r16 & 7) << 4;              // read-side XOR
    const int rdoff = (kg * 16) ^ xsw;             // logical col byte ^ swizzle

    // ---- staging: 8 lanes cover one row's 128B (fully coalesced); 4 slices of 64 rows
    const int srow  = tid >> 3;                    // 0..63, +64 per slice
    const int scolf = (tid & 7) * 4;               // float col within chunk
    const float* pg[4];
#pragma unroll
    for (int s = 0; s < 4; s++) {
        const int grow = BANDROW[flavor][s] * 64 + srow;
        pg[s] = X + (size_t)grow * D_FEAT + (size_t)strip * COLS_PER + scolf;
    }
    // LDS write byte offsets (XOR swizzle; 8B runs stay contiguous)
    const int wbase = srow * LROW + (((tid & 7) * 8) ^ ((srow & 7) << 4));

    f32x4 acc[4][4];
#pragma unroll
    for (int m = 0; m < 4; m++)
#pragma unroll
        for (int n = 0; n < 4; n++) acc[m][n] = (f32x4)(0.0f);

    float4 g[4];

#define LOADG(t)                                                                          \
    _Pragma("unroll") for (int s = 0; s < 4; s++)                                         \
        g[s] = *(const float4*)(pg[s] + (size_t)(t) * CHUNK);

#define WRITEL(buf)                                                                       \
    _Pragma("unroll") for (int s = 0; s < 4; s++) {                                       \
        bf16x4 v;                                                                         \
        v[0] = (__bf16)g[s].x; v[1] = (__bf16)g[s].y;                                     \
        v[2] = (__bf16)g[s].z; v[3] = (__bf16)g[s].w;                                     \
        *(bf16x4*)(&sm[buf][wbase + s * 64 * LROW]) = v;                                  \
    }

#define COMPUTE(buf)                                                                      \
    do {                                                                                  \
        const char* bptr = sm[buf];                                                       \
        bf16x8 af[4], bf[4];                                                              \
        _Pragma("unroll") for (int m = 0; m < 4; m++)                                     \
            af[m] = *(const bf16x8*)(bptr + (lrowA + m * 16 + r16) * LROW + rdoff);       \
        _Pragma("unroll") for (int n = 0; n < 4; n++)                                     \
            bf[n] = *(const bf16x8*)(bptr + (lrowB + n * 16 + r16) * LROW + rdoff);       \
        _Pragma("unroll") for (int m = 0; m < 4; m++)                                     \
            _Pragma("unroll") for (int n = 0; n < 4; n++)                                 \
                acc[m][n] = __builtin_amdgcn_mfma_f32_16x16x32_bf16(af[m], bf[n],         \
                                                                    acc[m][n], 0, 0, 0);  \
    } while (0)

    // prologue: chunk 0 staged, chunk 1 in flight
    LOADG(0);
    WRITEL(0);
    LOADG(1);
    __syncthreads();

    for (int t = 0; t < NCH; ++t) {
        const int cur = t & 1;
        COMPUTE(cur);                     // loads for t+1 stay in flight under this
        if (t + 1 < NCH) {
            WRITEL(cur ^ 1);              // waits vmcnt, cvt, stage next buffer
            if (t + 2 < NCH) LOADG(t + 2);
        }
        __syncthreads();
    }
#undef LOADG
#undef WRITEL
#undef COMPUTE

    // C/D layout (verified on gfx950): col = lane&15, row = (lane>>4)*4 + r
    const int orow = tI * 128 + (sub >> 1) * 64 + (lane >> 4) * 4;
    const int ocol = tJ * 128 + (sub & 1) * 64 + (lane & 15);
#pragma unroll
    for (int m = 0; m < 4; m++)
#pragma unroll
        for (int n = 0; n < 4; n++)
#pragma unroll
            for (int r = 0; r < 4; r++)
                atomicAdd(&G[(size_t)(orow + m * 16 + r) * N_TOTAL + ocol + n * 16],
                          acc[m][n][r]);
}

// ---------------- denominators and loss ----------------
__global__ __launch_bounds__(128) void den_kernel(const float* __restrict__ G,
                                                  float* __restrict__ den) {
    const int i = blockIdx.x;
    __shared__ float sInv[N_TOTAL];
    for (int j = threadIdx.x; j < N_TOTAL; j += 128) {
        const float n = sqrtf(G[(size_t)j * N_TOTAL + j]);
        sInv[j] = 1.0f / fmaxf(n, EPS);
    }
    __syncthreads();

    const float mi  = sInv[i] * 10.0f;   // 1/temp = 10
    const int   myc = i & 7;
    float s = 0.0f;
    for (int j = threadIdx.x; j < N_TOTAL; j += 128) {
        if ((j & 7) != myc)
            s += expf(gsym(G, i, j) * mi * sInv[j]);
    }
#pragma unroll
    for (int off = 32; off > 0; off >>= 1) s += __shfl_down(s, off, 64);
    __shared__ float partial[2];
    if ((threadIdx.x & 63) == 0) partial[threadIdx.x >> 6] = s;
    __syncthreads();
    if (threadIdx.x == 0) den[i] = partial[0] + partial[1];
}

__global__ __launch_bounds__(256) void loss_kernel(const float* __restrict__ G,
                                                   const float* __restrict__ den,
                                                   float* __restrict__ out) {
    __shared__ float sInv[N_TOTAL];
    for (int j = threadIdx.x; j < N_TOTAL; j += 256) {
        const float n = sqrtf(G[(size_t)j * N_TOTAL + j]);
        sInv[j] = 1.0f / fmaxf(n, EPS);
    }
    __syncthreads();

    float s = 0.0f;
    for (int idx = threadIdx.x; idx < 7 * BS; idx += 256) {
        const int p   = idx & (BS - 1);
        const int set = idx >> 7;
        int a, b;
        switch (set) {
            case 0:  a = p;                        b = BS + p;                      break;
            case 1:  a = (p + PD) % N_TOTAL;       b = (BS + p + PD) % N_TOTAL;     break;
            case 2:  a = p;                        b = (p + PD) % N_TOTAL;          break;
            case 3:  a = BS + p;                   b = (BS + p + PD) % N_TOTAL;     break;
            case 4:  a = 2 * BS + p;               b = (2 * BS + p + PD) % N_TOTAL; break;
            case 5:  a = BS + p;                   b = 2 * BS + p;                  break;
            default: a = (BS + p + PD) % N_TOTAL;  b = (2 * BS + p + PD) % N_TOTAL; break;
        }
        const float en = expf(gsym(G, a, b) * sInv[a] * sInv[b] * 10.0f);
        s += log1pf(den[a] / en) + log1pf(den[b] / en);
    }
#pragma unroll
    for (int off = 32; off > 0; off >>= 1) s += __shfl_down(s, off, 64);
    __shared__ float partial[4];
    if ((threadIdx.x & 63) == 0) partial[threadIdx.x >> 6] = s;
    __syncthreads();
    if (threadIdx.x == 0)
        out[0] = (partial[0] + partial[1] + partial[2] + partial[3]) / 768.0f;
}

extern "C" void kernel_launch(void* const* d_in, const int* in_sizes, int n_in,
                              void* d_out, int out_size, void* d_ws, size_t ws_size,
                              hipStream_t stream) {
    (void)in_sizes; (void)n_in; (void)out_size; (void)ws_size;
    const float* X   = (const float*)d_in[0];
    float*       out = (float*)d_out;
    float*       G   = (float*)d_ws;                       // 384*384 fp32
    float*       den = G + (size_t)N_TOTAL * N_TOTAL;      // 384 fp32

    hipMemsetAsync(G, 0, (size_t)N_TOTAL * N_TOTAL * sizeof(float), stream);
    gram_fused_kernel<<<NSTRIP * 3, 512, 0, stream>>>(X, G);
    den_kernel<<<N_TOTAL, 128, 0, stream>>>(G, den);
    loss_kernel<<<1, 256, 0, stream>>>(G, den, out);
}

// Round 8
// 77.784 us; speedup vs baseline: 1.8134x; 1.8134x over previous
//
#include <hip/hip_runtime.h>
#include <hip/hip_bf16.h>

#define N_TOTAL 384
#define BS 128
#define PD 8
#define D_FEAT 131072
#define EPS 1e-6f

#define NSTRIP 128
#define COLS_PER (D_FEAT / NSTRIP)   // 1024 cols per strip
#define CHUNK 32
#define NCH (COLS_PER / CHUNK)       // 32 chunks per strip
#define LROW 64                      // LDS row stride bytes, XOR-swizzled
#define NSLOT 12                     // partial subtiles per block
#define PSTRIDE (NSLOT * 4096)       // floats per block in P

typedef __attribute__((ext_vector_type(4))) float f32x4;
typedef __attribute__((ext_vector_type(8))) __bf16 bf16x8;
typedef __attribute__((ext_vector_type(4))) __bf16 bf16x4;

// Per-wave output subtile tables (64-row/col band indices, 0..5).
// flavor 0 = diagonal 128-tiles (0,0)(1,1)(2,2); flavor 1 = off-diag (0,1)(0,2)(1,2).
// Waves 0-3 own two col-bands sharing one row-band; waves 4-7 own one (CB1 = -1).
static __device__ const int RBt[16]  = {0,1,2,3,4,4,5,5,  0,1,0,1,2,2,3,3};
static __device__ const int CB0t[16] = {0,0,2,2,4,5,4,5,  2,2,4,4,4,5,4,5};
static __device__ const int CB1t[16] = {1,1,3,3,-1,-1,-1,-1,  3,3,5,5,-1,-1,-1,-1};

// Symmetric accessor: only upper-triangular 128-tiles of G are populated.
__device__ __forceinline__ float gsym(const float* __restrict__ G, int i, int j) {
    return ((i >> 7) <= (j >> 7)) ? G[(size_t)i * N_TOTAL + j]
                                  : G[(size_t)j * N_TOTAL + i];
}

// ---------------- stage A: read X once/strip, cvt in-reg, Gram partials (NO atomics) ----
__global__ __launch_bounds__(512, 2) void gram_fused_kernel(const float* __restrict__ X,
                                                            float* __restrict__ P) {
    __shared__ char sm[2][N_TOTAL * LROW];   // 2 x 24 KB, bf16 [384][32], XOR-swizzled

    // XCD swizzle: both flavors of a strip land on the same XCD (L2 pair-reuse).
    const int B      = blockIdx.x;
    const int x      = B & 7;
    const int i      = B >> 3;
    const int flavor = i & 1;
    const int strip  = x + 8 * (i >> 1);

    const int tid  = threadIdx.x;
    const int wave = tid >> 6;
    const int lane = tid & 63;
    const int r16  = lane & 15;
    const int kg   = lane >> 4;

    const int rb   = RBt[flavor * 8 + wave] * 64;
    const int cb0  = CB0t[flavor * 8 + wave] * 64;
    const int cb1s = CB1t[flavor * 8 + wave];
    const int cb1  = cb1s * 64;
    const int rdoff = (kg * 16) ^ ((r16 & 7) << 4);    // read-side XOR swizzle

    const size_t cbase = (size_t)strip * COLS_PER;
    const int srow  = tid >> 3;        // 0..63, +64 per slice (6 slices = 384 rows)
    const int scolf = (tid & 7) * 4;   // float col within chunk
    const int wbase = srow * LROW + (((tid & 7) * 8) ^ ((srow & 7) << 4));

    f32x4 acc0[4][4], acc1[4][4];
#pragma unroll
    for (int m = 0; m < 4; m++)
#pragma unroll
        for (int n = 0; n < 4; n++) { acc0[m][n] = (f32x4)(0.0f); acc1[m][n] = (f32x4)(0.0f); }

    float4 g[6];   // staged fp32 chunk: 6 float4/thread = 384x32 per block

#define LOADG(t)                                                                          \
    _Pragma("unroll") for (int s = 0; s < 6; s++)                                         \
        g[s] = *(const float4*)(X + (size_t)(srow + s * 64) * D_FEAT + cbase +            \
                                (size_t)(t) * CHUNK + scolf);

#define WRITEL(buf)                                                                       \
    _Pragma("unroll") for (int s = 0; s < 6; s++) {                                       \
        bf16x4 v;                                                                         \
        v[0] = (__bf16)g[s].x; v[1] = (__bf16)g[s].y;                                     \
        v[2] = (__bf16)g[s].z; v[3] = (__bf16)g[s].w;                                     \
        *(bf16x4*)(&sm[buf][wbase + s * 64 * LROW]) = v;                                  \
    }

#define COMPUTE(buf)                                                                      \
    do {                                                                                  \
        const char* bptr = sm[buf];                                                       \
        bf16x8 af[4], bf0[4];                                                             \
        _Pragma("unroll") for (int m = 0; m < 4; m++)                                     \
            af[m] = *(const bf16x8*)(bptr + (rb + m * 16 + r16) * LROW + rdoff);          \
        _Pragma("unroll") for (int n = 0; n < 4; n++)                                     \
            bf0[n] = *(const bf16x8*)(bptr + (cb0 + n * 16 + r16) * LROW + rdoff);        \
        _Pragma("unroll") for (int m = 0; m < 4; m++)                                     \
            _Pragma("unroll") for (int n = 0; n < 4; n++)                                 \
                acc0[m][n] = __builtin_amdgcn_mfma_f32_16x16x32_bf16(af[m], bf0[n],       \
                                                                     acc0[m][n], 0, 0, 0);\
        if (cb1s >= 0) {                                                                  \
            bf16x8 bf1[4];                                                                \
            _Pragma("unroll") for (int n = 0; n < 4; n++)                                 \
                bf1[n] = *(const bf16x8*)(bptr + (cb1 + n * 16 + r16) * LROW + rdoff);    \
            _Pragma("unroll") for (int m = 0; m < 4; m++)                                 \
                _Pragma("unroll") for (int n = 0; n < 4; n++)                             \
                    acc1[m][n] = __builtin_amdgcn_mfma_f32_16x16x32_bf16(af[m], bf1[n],   \
                                                                     acc1[m][n], 0, 0, 0);\
        }                                                                                 \
    } while (0)

    // prologue: chunk 0 staged, chunk 1 in flight
    LOADG(0);
    WRITEL(0);
    LOADG(1);
    __syncthreads();

    for (int t = 0; t < NCH; ++t) {
        const int cur = t & 1;
        COMPUTE(cur);                     // loads for t+1 stay in flight under this
        if (t + 1 < NCH) {
            WRITEL(cur ^ 1);              // waits vmcnt, cvt, stage next buffer
            if (t + 2 < NCH) LOADG(t + 2);
        }
        __syncthreads();
    }
#undef LOADG
#undef WRITEL
#undef COMPUTE

    // Epilogue: plain stores of per-wave 64x64 partials, col-major (f32x4 over rows).
    // C/D layout: ccol = lane&15, crow = (lane>>4)*4 + r.
    const int crow = (lane >> 4) * 4;
    const int ccol = lane & 15;
    float* base0 = P + ((size_t)(strip * 2 + flavor) * NSLOT + wave) * 4096;
#pragma unroll
    for (int m = 0; m < 4; m++)
#pragma unroll
        for (int n = 0; n < 4; n++)
            *(f32x4*)(base0 + (n * 16 + ccol) * 64 + m * 16 + crow) = acc0[m][n];
    if (cb1s >= 0) {
        float* base1 = P + ((size_t)(strip * 2 + flavor) * NSLOT + 8 + wave) * 4096;
#pragma unroll
        for (int m = 0; m < 4; m++)
#pragma unroll
            for (int n = 0; n < 4; n++)
                *(f32x4*)(base1 + (n * 16 + ccol) * 64 + m * 16 + crow) = acc1[m][n];
    }
}

// ---------------- stage B: reduce partials over 128 strips -> G ----------------
__global__ __launch_bounds__(256) void reduce_kernel(const float* __restrict__ P,
                                                     float* __restrict__ G) {
    const int b     = blockIdx.x;          // 0..383
    const int chunk = b & 15;              // 16 chunks of 256 elems
    const int sg    = b >> 4;              // 0..23 = flavor*12 + slot
    const int f     = sg / NSLOT;
    const int slot  = sg % NSLOT;
    const int e     = chunk * 256 + threadIdx.x;   // 0..4095

    const float* p = P + ((size_t)f * NSLOT + slot) * 4096 + e;
    float s = 0.0f;
#pragma unroll 8
    for (int strip = 0; strip < NSTRIP; ++strip)
        s += p[(size_t)strip * 2 * PSTRIDE];

    const int w     = (slot < 8) ? slot : slot - 8;
    const int rb    = RBt[f * 8 + w] * 64;
    const int cb    = ((slot < 8) ? CB0t[f * 8 + w] : CB1t[f * 8 + w]) * 64;
    const int col   = e >> 6;
    const int row   = e & 63;
    G[(size_t)(rb + row) * N_TOTAL + cb + col] = s;
}

// ---------------- denominators and loss ----------------
__global__ __launch_bounds__(128) void den_kernel(const float* __restrict__ G,
                                                  float* __restrict__ den) {
    const int i = blockIdx.x;
    __shared__ float sInv[N_TOTAL];
    for (int j = threadIdx.x; j < N_TOTAL; j += 128) {
        const float n = sqrtf(G[(size_t)j * N_TOTAL + j]);
        sInv[j] = 1.0f / fmaxf(n, EPS);
    }
    __syncthreads();

    const float mi  = sInv[i] * 10.0f;   // 1/temp = 10
    const int   myc = i & 7;
    float s = 0.0f;
    for (int j = threadIdx.x; j < N_TOTAL; j += 128) {
        if ((j & 7) != myc)
            s += expf(gsym(G, i, j) * mi * sInv[j]);
    }
#pragma unroll
    for (int off = 32; off > 0; off >>= 1) s += __shfl_down(s, off, 64);
    __shared__ float partial[2];
    if ((threadIdx.x & 63) == 0) partial[threadIdx.x >> 6] = s;
    __syncthreads();
    if (threadIdx.x == 0) den[i] = partial[0] + partial[1];
}

__global__ __launch_bounds__(256) void loss_kernel(const float* __restrict__ G,
                                                   const float* __restrict__ den,
                                                   float* __restrict__ out) {
    __shared__ float sInv[N_TOTAL];
    for (int j = threadIdx.x; j < N_TOTAL; j += 256) {
        const float n = sqrtf(G[(size_t)j * N_TOTAL + j]);
        sInv[j] = 1.0f / fmaxf(n, EPS);
    }
    __syncthreads();

    float s = 0.0f;
    for (int idx = threadIdx.x; idx < 7 * BS; idx += 256) {
        const int p   = idx & (BS - 1);
        const int set = idx >> 7;
        int a, b;
        switch (set) {
            case 0:  a = p;                        b = BS + p;                      break;
            case 1:  a = (p + PD) % N_TOTAL;       b = (BS + p + PD) % N_TOTAL;     break;
            case 2:  a = p;                        b = (p + PD) % N_TOTAL;          break;
            case 3:  a = BS + p;                   b = (BS + p + PD) % N_TOTAL;     break;
            case 4:  a = 2 * BS + p;               b = (2 * BS + p + PD) % N_TOTAL; break;
            case 5:  a = BS + p;                   b = 2 * BS + p;                  break;
            default: a = (BS + p + PD) % N_TOTAL;  b = (2 * BS + p + PD) % N_TOTAL; break;
        }
        const float en = expf(gsym(G, a, b) * sInv[a] * sInv[b] * 10.0f);
        s += log1pf(den[a] / en) + log1pf(den[b] / en);
    }
#pragma unroll
    for (int off = 32; off > 0; off >>= 1) s += __shfl_down(s, off, 64);
    __shared__ float partial[4];
    if ((threadIdx.x & 63) == 0) partial[threadIdx.x >> 6] = s;
    __syncthreads();
    if (threadIdx.x == 0)
        out[0] = (partial[0] + partial[1] + partial[2] + partial[3]) / 768.0f;
}

extern "C" void kernel_launch(void* const* d_in, const int* in_sizes, int n_in,
                              void* d_out, int out_size, void* d_ws, size_t ws_size,
                              hipStream_t stream) {
    (void)in_sizes; (void)n_in; (void)out_size; (void)ws_size;
    const float* X   = (const float*)d_in[0];
    float*       out = (float*)d_out;
    float*       G   = (float*)d_ws;                         // 384*384 fp32
    float*       den = G + (size_t)N_TOTAL * N_TOTAL;        // 384 fp32
    float*       P   = (float*)((char*)d_ws + (1u << 20));   // 256 * 12 * 4096 fp32 = 48 MB

    gram_fused_kernel<<<NSTRIP * 2, 512, 0, stream>>>(X, P);
    reduce_kernel<<<384, 256, 0, stream>>>(P, G);
    den_kernel<<<N_TOTAL, 128, 0, stream>>>(G, den);
    loss_kernel<<<1, 256, 0, stream>>>(G, den, out);
}